// Round 2
// baseline (568.045 us; speedup 1.0000x reference)
//
#include <hip/hip_runtime.h>
#include <hip/hip_bf16.h>

#define EMB_D   768
#define N_SLOTS 16
#define KEY_D   64
#define N_ITER  3
#define BS      128
#define N_TOK   196
#define N_ROWS  (BS * N_TOK)      // 25088
#define PROMPT_N (5 * 8 * EMB_D)  // 30720
#define TOT_SLOT_ROWS (BS * N_SLOTS) // 2048

__device__ __forceinline__ float sigmoid_f(float x) { return 1.f / (1.f + __expf(-x)); }
__device__ __forceinline__ float tanh_f(float x)    { return 1.f - 2.f / (__expf(2.f * x) + 1.f); }

// ---------------------------------------------------------------------------
// Kernel A: f = LN(features); k = f@Wk; v = f@Wv
// 32 token-rows per block, 256 threads. LDS holds normalized rows.
// ---------------------------------------------------------------------------
__global__ __launch_bounds__(256) void kv_kernel(
    const float* __restrict__ feat, const float* __restrict__ lnw,
    const float* __restrict__ lnb, const float* __restrict__ Wk,
    const float* __restrict__ Wv, float* __restrict__ kbuf,
    float* __restrict__ vbuf)
{
    __shared__ float fl[32][EMB_D]; // 96 KB
    const int t = threadIdx.x;
    const int rowbase = blockIdx.x * 32;
    const int wave = t >> 6, lane = t & 63;

    // hoist LN weights for this lane's 12 columns
    float wl[12], bl[12];
    #pragma unroll
    for (int j = 0; j < 12; ++j) { wl[j] = lnw[lane + 64 * j]; bl[j] = lnb[lane + 64 * j]; }

    // LN phase: 8 rows per wave
    for (int rr = 0; rr < 8; ++rr) {
        const int r = wave + 4 * rr;
        const int row = rowbase + r;
        const float* fr = feat + (size_t)row * EMB_D;
        float x[12];
        float s = 0.f, ss = 0.f;
        #pragma unroll
        for (int j = 0; j < 12; ++j) {
            x[j] = fr[lane + 64 * j];
            s += x[j]; ss += x[j] * x[j];
        }
        #pragma unroll
        for (int m = 32; m >= 1; m >>= 1) { s += __shfl_xor(s, m, 64); ss += __shfl_xor(ss, m, 64); }
        const float mean = s * (1.f / EMB_D);
        const float var  = ss * (1.f / EMB_D) - mean * mean;
        const float rstd = rsqrtf(var + 1e-5f);
        #pragma unroll
        for (int j = 0; j < 12; ++j)
            fl[r][lane + 64 * j] = (x[j] - mean) * rstd * wl[j] + bl[j];
    }
    __syncthreads();

    // GEMM phase: 4x4 register tile per thread
    const int rg = t >> 5;   // 0..7 -> rows rg*4..+3
    const int cg = t & 31;   // 0..31 -> 16 groups for k, 16 for v
    const float* W = (cg < 16) ? Wk : Wv;
    float* outb    = (cg < 16) ? kbuf : vbuf;
    const int cb = (cg & 15) * 4;

    float acc[4][4];
    #pragma unroll
    for (int i = 0; i < 4; ++i)
        #pragma unroll
        for (int c = 0; c < 4; ++c) acc[i][c] = 0.f;

    for (int k0 = 0; k0 < EMB_D; k0 += 4) {
        float f[4][4], w[4][4];
        #pragma unroll
        for (int i = 0; i < 4; ++i)
            *(float4*)&f[i][0] = *(const float4*)&fl[rg * 4 + i][k0];
        #pragma unroll
        for (int kk = 0; kk < 4; ++kk)
            *(float4*)&w[kk][0] = *(const float4*)&W[(size_t)(k0 + kk) * 64 + cb];
        #pragma unroll
        for (int i = 0; i < 4; ++i)
            #pragma unroll
            for (int kk = 0; kk < 4; ++kk)
                #pragma unroll
                for (int c = 0; c < 4; ++c)
                    acc[i][c] = fmaf(f[i][kk], w[kk][c], acc[i][c]);
    }
    #pragma unroll
    for (int i = 0; i < 4; ++i)
        *(float4*)&outb[(size_t)(rowbase + rg * 4 + i) * 64 + cb] = *(const float4*)&acc[i][0];
}

// ---------------------------------------------------------------------------
// Kernel B: per-batch slot-attention iterations (one block per batch)
// ---------------------------------------------------------------------------
__global__ __launch_bounds__(256) void iter_kernel(
    const float* __restrict__ kbuf, const float* __restrict__ vbuf,
    const float* __restrict__ noise, const float* __restrict__ mu,
    const float* __restrict__ sigma,
    const float* __restrict__ lnsw, const float* __restrict__ lnsb,
    const float* __restrict__ lnow, const float* __restrict__ lnob,
    const float* __restrict__ Wq,
    const float* __restrict__ W_ih, const float* __restrict__ W_hh,
    const float* __restrict__ b_ih, const float* __restrict__ b_hh,
    const float* __restrict__ W1, const float* __restrict__ b1,
    const float* __restrict__ W2, const float* __restrict__ b2,
    float* __restrict__ slots_T)
{
    __shared__ float k_l[N_TOK][68];      // 53.3 KB
    __shared__ float att[N_SLOTS][200];   // [s][n], 12.8 KB
    __shared__ float slots[N_SLOTS][68];
    __shared__ float sp[N_SLOTS][68];
    __shared__ float lnbuf[N_SLOTS][68];
    __shared__ float qb[N_SLOTS][68];
    __shared__ float upd[N_SLOTS][68];
    __shared__ float mlp_l[N_SLOTS][68];
    __shared__ float gi_l[N_SLOTS][200];
    __shared__ float gh_l[N_SLOTS][200];
    __shared__ float partial[16][17];
    __shared__ float inv_cs[16];

    const int b = blockIdx.x;
    const int t = threadIdx.x;

    // stage k tile
    for (int idx = t; idx < N_TOK * 64; idx += 256)
        k_l[idx >> 6][idx & 63] = kbuf[((size_t)b * N_TOK + (idx >> 6)) * 64 + (idx & 63)];

    // init slots = noise*sigma + mu
    {
        const int s = t >> 4, d0 = (t & 15) * 4;
        #pragma unroll
        for (int dd = 0; dd < 4; ++dd) {
            const int d = d0 + dd;
            slots[s][d] = noise[((size_t)b * 16 + s) * 64 + d] * sigma[d] + mu[d];
        }
    }
    __syncthreads();

    const float* vb = vbuf + (size_t)b * N_TOK * 64;

    for (int it = 0; it < N_ITER; ++it) {
        // sp = slots
        {
            const int s = t >> 4, d0 = (t & 15) * 4;
            *(float4*)&sp[s][d0] = *(const float4*)&slots[s][d0];
        }
        __syncthreads();

        // LN(slots) with ln_slot -> lnbuf
        {
            const int s = t >> 4, j = t & 15;
            const float4 x = *(const float4*)&slots[s][j * 4];
            float sum = x.x + x.y + x.z + x.w;
            float ssm = x.x * x.x + x.y * x.y + x.z * x.z + x.w * x.w;
            #pragma unroll
            for (int m = 8; m >= 1; m >>= 1) { sum += __shfl_xor(sum, m, 64); ssm += __shfl_xor(ssm, m, 64); }
            const float mean = sum * (1.f / 64);
            const float rstd = rsqrtf(ssm * (1.f / 64) - mean * mean + 1e-5f);
            const int d0 = j * 4;
            lnbuf[s][d0 + 0] = (x.x - mean) * rstd * lnsw[d0 + 0] + lnsb[d0 + 0];
            lnbuf[s][d0 + 1] = (x.y - mean) * rstd * lnsw[d0 + 1] + lnsb[d0 + 1];
            lnbuf[s][d0 + 2] = (x.z - mean) * rstd * lnsw[d0 + 2] + lnsb[d0 + 2];
            lnbuf[s][d0 + 3] = (x.w - mean) * rstd * lnsw[d0 + 3] + lnsb[d0 + 3];
        }
        __syncthreads();

        // q = lnbuf @ Wq, scaled by 1/sqrt(64)
        {
            const int o = t & 63, wq = t >> 6;
            float acc[4] = {0.f, 0.f, 0.f, 0.f};
            for (int i = 0; i < 64; ++i) {
                const float wv = Wq[i * 64 + o];
                #pragma unroll
                for (int si = 0; si < 4; ++si) acc[si] = fmaf(lnbuf[wq * 4 + si][i], wv, acc[si]);
            }
            #pragma unroll
            for (int si = 0; si < 4; ++si) qb[wq * 4 + si][o] = acc[si] * 0.125f;
        }
        __syncthreads();

        // logits: att[s][n] = k[n] . q[s]
        {
            const int n0 = t >> 4, s = t & 15;
            float4 qr[16];
            #pragma unroll
            for (int dq = 0; dq < 16; ++dq) qr[dq] = *(const float4*)&qb[s][dq * 4];
            for (int n = n0; n < N_TOK; n += 16) {
                float acc = 0.f;
                #pragma unroll
                for (int dq = 0; dq < 16; ++dq) {
                    const float4 k4 = *(const float4*)&k_l[n][dq * 4];
                    acc += k4.x * qr[dq].x + k4.y * qr[dq].y + k4.z * qr[dq].z + k4.w * qr[dq].w;
                }
                att[s][n] = acc;
            }
        }
        __syncthreads();

        // softmax over slots for each token + eps
        if (t < N_TOK) {
            float m = -1e30f;
            #pragma unroll
            for (int s = 0; s < 16; ++s) m = fmaxf(m, att[s][t]);
            float e[16], sum = 0.f;
            #pragma unroll
            for (int s = 0; s < 16; ++s) { e[s] = __expf(att[s][t] - m); sum += e[s]; }
            const float inv = 1.f / sum;
            #pragma unroll
            for (int s = 0; s < 16; ++s) att[s][t] = e[s] * inv + 1e-8f;
        }
        __syncthreads();

        // column (token) sums per slot
        {
            const int s = t & 15, n0 = t >> 4;
            float p = 0.f;
            for (int n = n0; n < N_TOK; n += 16) p += att[s][n];
            partial[n0][s] = p;
        }
        __syncthreads();
        if (t < 16) {
            float cs = 0.f;
            #pragma unroll
            for (int n0 = 0; n0 < 16; ++n0) cs += partial[n0][t];
            inv_cs[t] = 1.f / cs;
        }
        __syncthreads();

        // updates[s][d] = (sum_n att[s][n] * v[n][d]) * inv_cs[s]
        {
            const int d = t & 63, wq = t >> 6;
            float acc[4] = {0.f, 0.f, 0.f, 0.f};
            for (int n4 = 0; n4 < N_TOK; n4 += 4) {
                float vv[4];
                #pragma unroll
                for (int j = 0; j < 4; ++j) vv[j] = vb[(size_t)(n4 + j) * 64 + d];
                #pragma unroll
                for (int si = 0; si < 4; ++si) {
                    const float4 a4 = *(const float4*)&att[wq * 4 + si][n4];
                    acc[si] += a4.x * vv[0] + a4.y * vv[1] + a4.z * vv[2] + a4.w * vv[3];
                }
            }
            #pragma unroll
            for (int si = 0; si < 4; ++si)
                upd[wq * 4 + si][d] = acc[si] * inv_cs[wq * 4 + si];
        }
        __syncthreads();

        // GRU gates: gi = upd @ W_ih^T + b_ih ; gh = sp @ W_hh^T + b_hh
        {
            const int s = t >> 4, g0 = t & 15;
            float accI[12], accH[12];
            #pragma unroll
            for (int j = 0; j < 12; ++j) { accI[j] = b_ih[g0 + 16 * j]; accH[j] = b_hh[g0 + 16 * j]; }
            for (int dq = 0; dq < 16; ++dq) {
                const float4 u4 = *(const float4*)&upd[s][dq * 4];
                const float4 h4 = *(const float4*)&sp[s][dq * 4];
                #pragma unroll
                for (int j = 0; j < 12; ++j) {
                    const int g = g0 + 16 * j;
                    const float4 wi = *(const float4*)&W_ih[(size_t)g * 64 + dq * 4];
                    const float4 wh = *(const float4*)&W_hh[(size_t)g * 64 + dq * 4];
                    accI[j] += u4.x * wi.x + u4.y * wi.y + u4.z * wi.z + u4.w * wi.w;
                    accH[j] += h4.x * wh.x + h4.y * wh.y + h4.z * wh.z + h4.w * wh.w;
                }
            }
            #pragma unroll
            for (int j = 0; j < 12; ++j) { gi_l[s][g0 + 16 * j] = accI[j]; gh_l[s][g0 + 16 * j] = accH[j]; }
        }
        __syncthreads();

        // combine gates -> new slots (GRU cell)
        {
            const int s = t >> 4, d0 = t & 15;
            #pragma unroll
            for (int m = 0; m < 4; ++m) {
                const int d = d0 + 16 * m;
                const float r  = sigmoid_f(gi_l[s][d] + gh_l[s][d]);
                const float z  = sigmoid_f(gi_l[s][64 + d] + gh_l[s][64 + d]);
                const float nc = tanh_f(gi_l[s][128 + d] + r * gh_l[s][128 + d]);
                slots[s][d] = (1.f - z) * nc + z * sp[s][d];
            }
        }
        __syncthreads();

        // LN(slots) with ln_out -> lnbuf
        {
            const int s = t >> 4, j = t & 15;
            const float4 x = *(const float4*)&slots[s][j * 4];
            float sum = x.x + x.y + x.z + x.w;
            float ssm = x.x * x.x + x.y * x.y + x.z * x.z + x.w * x.w;
            #pragma unroll
            for (int m = 8; m >= 1; m >>= 1) { sum += __shfl_xor(sum, m, 64); ssm += __shfl_xor(ssm, m, 64); }
            const float mean = sum * (1.f / 64);
            const float rstd = rsqrtf(ssm * (1.f / 64) - mean * mean + 1e-5f);
            const int d0 = j * 4;
            lnbuf[s][d0 + 0] = (x.x - mean) * rstd * lnow[d0 + 0] + lnob[d0 + 0];
            lnbuf[s][d0 + 1] = (x.y - mean) * rstd * lnow[d0 + 1] + lnob[d0 + 1];
            lnbuf[s][d0 + 2] = (x.z - mean) * rstd * lnow[d0 + 2] + lnob[d0 + 2];
            lnbuf[s][d0 + 3] = (x.w - mean) * rstd * lnow[d0 + 3] + lnob[d0 + 3];
        }
        __syncthreads();

        // mlp1 = relu(lnbuf @ W1^T + b1)
        {
            const int o = t & 63, wq = t >> 6;
            float acc[4];
            #pragma unroll
            for (int si = 0; si < 4; ++si) acc[si] = b1[o];
            for (int iq = 0; iq < 16; ++iq) {
                const float4 w4 = *(const float4*)&W1[(size_t)o * 64 + iq * 4];
                #pragma unroll
                for (int si = 0; si < 4; ++si) {
                    const float4 l4 = *(const float4*)&lnbuf[wq * 4 + si][iq * 4];
                    acc[si] += l4.x * w4.x + l4.y * w4.y + l4.z * w4.z + l4.w * w4.w;
                }
            }
            #pragma unroll
            for (int si = 0; si < 4; ++si) mlp_l[wq * 4 + si][o] = fmaxf(acc[si], 0.f);
        }
        __syncthreads();

        // slots += mlp_l @ W2^T + b2
        {
            const int o = t & 63, wq = t >> 6;
            float acc[4];
            #pragma unroll
            for (int si = 0; si < 4; ++si) acc[si] = b2[o];
            for (int iq = 0; iq < 16; ++iq) {
                const float4 w4 = *(const float4*)&W2[(size_t)o * 64 + iq * 4];
                #pragma unroll
                for (int si = 0; si < 4; ++si) {
                    const float4 l4 = *(const float4*)&mlp_l[wq * 4 + si][iq * 4];
                    acc[si] += l4.x * w4.x + l4.y * w4.y + l4.z * w4.z + l4.w * w4.w;
                }
            }
            #pragma unroll
            for (int si = 0; si < 4; ++si) slots[wq * 4 + si][o] += acc[si];
        }
        __syncthreads();
    }

    // write slots transposed: slots_T[d][b*16+s]
    {
        const int s = t >> 4, d0 = (t & 15) * 4;
        #pragma unroll
        for (int dd = 0; dd < 4; ++dd)
            slots_T[(size_t)(d0 + dd) * TOT_SLOT_ROWS + b * 16 + s] = slots[s][d0 + dd];
    }
}

// ---------------------------------------------------------------------------
// Kernel C: prompts[row][n] = sum_h slots[row][h] * s2p[h][n]  (f32 out)
// 64 rows per block (slots uniform -> scalar loads), 2048 cols per block.
// ---------------------------------------------------------------------------
__global__ __launch_bounds__(256) void prompt_kernel(
    const float* __restrict__ slots_T, const float* __restrict__ s2p,
    float* __restrict__ out)
{
    const int rowgrp = blockIdx.x / 15;  // 0..31
    const int colgrp = blockIdx.x % 15;  // 0..14
    const int t = threadIdx.x;
    const int rowbase = rowgrp * 64;

    #pragma unroll 1
    for (int j = 0; j < 8; ++j) {
        const int n = colgrp * 2048 + j * 256 + t;
        float acc[64];
        #pragma unroll
        for (int r = 0; r < 64; ++r) acc[r] = 0.f;
        #pragma unroll 1
        for (int h = 0; h < 64; ++h) {
            const float sv = s2p[(size_t)h * PROMPT_N + n];
            const float* sl = slots_T + (size_t)h * TOT_SLOT_ROWS + rowbase;
            #pragma unroll
            for (int r = 0; r < 64; ++r) acc[r] = fmaf(sl[r], sv, acc[r]);
        }
        #pragma unroll
        for (int r = 0; r < 64; ++r)
            out[(size_t)(rowbase + r) * PROMPT_N + n] = acc[r];
    }
}

// ---------------------------------------------------------------------------
extern "C" void kernel_launch(void* const* d_in, const int* in_sizes, int n_in,
                              void* d_out, int out_size, void* d_ws, size_t ws_size,
                              hipStream_t stream)
{
    (void)in_sizes; (void)n_in; (void)out_size; (void)ws_size;
    const float* feat    = (const float*)d_in[0];
    const float* noise   = (const float*)d_in[1];
    const float* ln_in_w = (const float*)d_in[2];
    const float* ln_in_b = (const float*)d_in[3];
    const float* ln_s_w  = (const float*)d_in[4];
    const float* ln_s_b  = (const float*)d_in[5];
    const float* ln_o_w  = (const float*)d_in[6];
    const float* ln_o_b  = (const float*)d_in[7];
    const float* mu      = (const float*)d_in[8];
    const float* sigma   = (const float*)d_in[9];
    const float* Wk      = (const float*)d_in[10];
    const float* Wq      = (const float*)d_in[11];
    const float* Wv      = (const float*)d_in[12];
    const float* W_ih    = (const float*)d_in[13];
    const float* W_hh    = (const float*)d_in[14];
    const float* b_ih    = (const float*)d_in[15];
    const float* b_hh    = (const float*)d_in[16];
    const float* W1      = (const float*)d_in[17];
    const float* b1      = (const float*)d_in[18];
    const float* W2      = (const float*)d_in[19];
    const float* b2      = (const float*)d_in[20];
    const float* s2p     = (const float*)d_in[21];

    float* kbuf    = (float*)d_ws;
    float* vbuf    = kbuf + (size_t)N_ROWS * 64;
    float* slots_T = vbuf + (size_t)N_ROWS * 64;

    hipLaunchKernelGGL(kv_kernel, dim3(N_ROWS / 32), dim3(256), 0, stream,
                       feat, ln_in_w, ln_in_b, Wk, Wv, kbuf, vbuf);
    hipLaunchKernelGGL(iter_kernel, dim3(BS), dim3(256), 0, stream,
                       kbuf, vbuf, noise, mu, sigma, ln_s_w, ln_s_b, ln_o_w, ln_o_b,
                       Wq, W_ih, W_hh, b_ih, b_hh, W1, b1, W2, b2, slots_T);
    hipLaunchKernelGGL(prompt_kernel, dim3(32 * 15), dim3(256), 0, stream,
                       slots_T, s2p, (float*)d_out);
}

// Round 3
// 509.959 us; speedup vs baseline: 1.1139x; 1.1139x over previous
//
#include <hip/hip_runtime.h>
#include <hip/hip_bf16.h>

#define EMB_D   768
#define N_SLOTS 16
#define KEY_D   64
#define N_ITER  3
#define BS      128
#define N_TOK   196
#define N_ROWS  (BS * N_TOK)      // 25088
#define PROMPT_N (5 * 8 * EMB_D)  // 30720
#define TOT_SLOT_ROWS (BS * N_SLOTS) // 2048

__device__ __forceinline__ float sigmoid_f(float x) { return 1.f / (1.f + __expf(-x)); }
__device__ __forceinline__ float tanh_f(float x)    { return 1.f - 2.f / (__expf(2.f * x) + 1.f); }

// ---------------------------------------------------------------------------
// Kernel A: f = LN(features); k = f@Wk; v = f@Wv
// 16 token-rows per block (49.4 KB LDS -> 3 blocks/CU), 256 threads.
// ---------------------------------------------------------------------------
__global__ __launch_bounds__(256) void kv_kernel(
    const float* __restrict__ feat, const float* __restrict__ lnw,
    const float* __restrict__ lnb, const float* __restrict__ Wk,
    const float* __restrict__ Wv, float* __restrict__ kbuf,
    float* __restrict__ vbuf)
{
    __shared__ float fl[16][772]; // 49.4 KB, padded stride (772 % 8 == 4) for banking
    const int t = threadIdx.x;
    const int rowbase = blockIdx.x * 16;
    const int wave = t >> 6, lane = t & 63;

    // hoist LN weights for this lane's 12 columns
    float wl[12], bl[12];
    #pragma unroll
    for (int j = 0; j < 12; ++j) { wl[j] = lnw[lane + 64 * j]; bl[j] = lnb[lane + 64 * j]; }

    // LN phase: 4 rows per wave
    #pragma unroll
    for (int rr = 0; rr < 4; ++rr) {
        const int r = wave + 4 * rr;
        const int row = rowbase + r;
        const float* fr = feat + (size_t)row * EMB_D;
        float x[12];
        float s = 0.f, ss = 0.f;
        #pragma unroll
        for (int j = 0; j < 12; ++j) {
            x[j] = fr[lane + 64 * j];
            s += x[j]; ss += x[j] * x[j];
        }
        #pragma unroll
        for (int m = 32; m >= 1; m >>= 1) { s += __shfl_xor(s, m, 64); ss += __shfl_xor(ss, m, 64); }
        const float mean = s * (1.f / EMB_D);
        const float var  = ss * (1.f / EMB_D) - mean * mean;
        const float rstd = rsqrtf(var + 1e-5f);
        #pragma unroll
        for (int j = 0; j < 12; ++j)
            fl[r][lane + 64 * j] = (x[j] - mean) * rstd * wl[j] + bl[j];
    }
    __syncthreads();

    // GEMM phase: 2 rows x 4 cols per thread
    const int rg = t >> 5;   // 0..7 -> rows {2rg, 2rg+1}
    const int cg = t & 31;   // 0..15 -> Wk cols, 16..31 -> Wv cols
    const float* W = (cg < 16) ? Wk : Wv;
    float* outb    = (cg < 16) ? kbuf : vbuf;
    const int cb = (cg & 15) * 4;

    float acc[2][4];
    #pragma unroll
    for (int i = 0; i < 2; ++i)
        #pragma unroll
        for (int c = 0; c < 4; ++c) acc[i][c] = 0.f;

    #pragma unroll 2
    for (int k0 = 0; k0 < EMB_D; k0 += 4) {
        float f[2][4], w[4][4];
        #pragma unroll
        for (int i = 0; i < 2; ++i)
            *(float4*)&f[i][0] = *(const float4*)&fl[rg * 2 + i][k0];
        #pragma unroll
        for (int kk = 0; kk < 4; ++kk)
            *(float4*)&w[kk][0] = *(const float4*)&W[(size_t)(k0 + kk) * 64 + cb];
        #pragma unroll
        for (int i = 0; i < 2; ++i)
            #pragma unroll
            for (int kk = 0; kk < 4; ++kk)
                #pragma unroll
                for (int c = 0; c < 4; ++c)
                    acc[i][c] = fmaf(f[i][kk], w[kk][c], acc[i][c]);
    }
    #pragma unroll
    for (int i = 0; i < 2; ++i)
        *(float4*)&outb[(size_t)(rowbase + rg * 2 + i) * 64 + cb] = *(const float4*)&acc[i][0];
}

// ---------------------------------------------------------------------------
// Kernel B: per-batch slot-attention iterations (one block per batch)
// ---------------------------------------------------------------------------
__global__ __launch_bounds__(256) void iter_kernel(
    const float* __restrict__ kbuf, const float* __restrict__ vbuf,
    const float* __restrict__ noise, const float* __restrict__ mu,
    const float* __restrict__ sigma,
    const float* __restrict__ lnsw, const float* __restrict__ lnsb,
    const float* __restrict__ lnow, const float* __restrict__ lnob,
    const float* __restrict__ Wq,
    const float* __restrict__ W_ih, const float* __restrict__ W_hh,
    const float* __restrict__ b_ih, const float* __restrict__ b_hh,
    const float* __restrict__ W1, const float* __restrict__ b1,
    const float* __restrict__ W2, const float* __restrict__ b2,
    float* __restrict__ slots_T)
{
    __shared__ float k_l[N_TOK][68];      // 53.3 KB
    __shared__ float att[N_SLOTS][200];   // [s][n], 12.8 KB
    __shared__ float slots[N_SLOTS][68];
    __shared__ float sp[N_SLOTS][68];
    __shared__ float lnbuf[N_SLOTS][68];
    __shared__ float qb[N_SLOTS][68];
    __shared__ float upd[N_SLOTS][68];
    __shared__ float mlp_l[N_SLOTS][68];
    __shared__ float gi_l[N_SLOTS][200];
    __shared__ float gh_l[N_SLOTS][200];
    __shared__ float partial[16][17];
    __shared__ float inv_cs[16];

    const int b = blockIdx.x;
    const int t = threadIdx.x;

    // stage k tile
    for (int idx = t; idx < N_TOK * 64; idx += 256)
        k_l[idx >> 6][idx & 63] = kbuf[((size_t)b * N_TOK + (idx >> 6)) * 64 + (idx & 63)];

    // init slots = noise*sigma + mu
    {
        const int s = t >> 4, d0 = (t & 15) * 4;
        #pragma unroll
        for (int dd = 0; dd < 4; ++dd) {
            const int d = d0 + dd;
            slots[s][d] = noise[((size_t)b * 16 + s) * 64 + d] * sigma[d] + mu[d];
        }
    }
    __syncthreads();

    const float* vb = vbuf + (size_t)b * N_TOK * 64;

    for (int it = 0; it < N_ITER; ++it) {
        // sp = slots
        {
            const int s = t >> 4, d0 = (t & 15) * 4;
            *(float4*)&sp[s][d0] = *(const float4*)&slots[s][d0];
        }
        __syncthreads();

        // LN(slots) with ln_slot -> lnbuf
        {
            const int s = t >> 4, j = t & 15;
            const float4 x = *(const float4*)&slots[s][j * 4];
            float sum = x.x + x.y + x.z + x.w;
            float ssm = x.x * x.x + x.y * x.y + x.z * x.z + x.w * x.w;
            #pragma unroll
            for (int m = 8; m >= 1; m >>= 1) { sum += __shfl_xor(sum, m, 64); ssm += __shfl_xor(ssm, m, 64); }
            const float mean = sum * (1.f / 64);
            const float rstd = rsqrtf(ssm * (1.f / 64) - mean * mean + 1e-5f);
            const int d0 = j * 4;
            lnbuf[s][d0 + 0] = (x.x - mean) * rstd * lnsw[d0 + 0] + lnsb[d0 + 0];
            lnbuf[s][d0 + 1] = (x.y - mean) * rstd * lnsw[d0 + 1] + lnsb[d0 + 1];
            lnbuf[s][d0 + 2] = (x.z - mean) * rstd * lnsw[d0 + 2] + lnsb[d0 + 2];
            lnbuf[s][d0 + 3] = (x.w - mean) * rstd * lnsw[d0 + 3] + lnsb[d0 + 3];
        }
        __syncthreads();

        // q = lnbuf @ Wq, scaled by 1/sqrt(64)
        {
            const int o = t & 63, wq = t >> 6;
            float acc[4] = {0.f, 0.f, 0.f, 0.f};
            for (int i = 0; i < 64; ++i) {
                const float wv = Wq[i * 64 + o];
                #pragma unroll
                for (int si = 0; si < 4; ++si) acc[si] = fmaf(lnbuf[wq * 4 + si][i], wv, acc[si]);
            }
            #pragma unroll
            for (int si = 0; si < 4; ++si) qb[wq * 4 + si][o] = acc[si] * 0.125f;
        }
        __syncthreads();

        // logits: att[s][n] = k[n] . q[s]
        {
            const int n0 = t >> 4, s = t & 15;
            float4 qr[16];
            #pragma unroll
            for (int dq = 0; dq < 16; ++dq) qr[dq] = *(const float4*)&qb[s][dq * 4];
            for (int n = n0; n < N_TOK; n += 16) {
                float acc = 0.f;
                #pragma unroll
                for (int dq = 0; dq < 16; ++dq) {
                    const float4 k4 = *(const float4*)&k_l[n][dq * 4];
                    acc += k4.x * qr[dq].x + k4.y * qr[dq].y + k4.z * qr[dq].z + k4.w * qr[dq].w;
                }
                att[s][n] = acc;
            }
        }
        __syncthreads();

        // softmax over slots for each token + eps
        if (t < N_TOK) {
            float m = -1e30f;
            #pragma unroll
            for (int s = 0; s < 16; ++s) m = fmaxf(m, att[s][t]);
            float e[16], sum = 0.f;
            #pragma unroll
            for (int s = 0; s < 16; ++s) { e[s] = __expf(att[s][t] - m); sum += e[s]; }
            const float inv = 1.f / sum;
            #pragma unroll
            for (int s = 0; s < 16; ++s) att[s][t] = e[s] * inv + 1e-8f;
        }
        __syncthreads();

        // column (token) sums per slot
        {
            const int s = t & 15, n0 = t >> 4;
            float p = 0.f;
            for (int n = n0; n < N_TOK; n += 16) p += att[s][n];
            partial[n0][s] = p;
        }
        __syncthreads();
        if (t < 16) {
            float cs = 0.f;
            #pragma unroll
            for (int n0 = 0; n0 < 16; ++n0) cs += partial[n0][t];
            inv_cs[t] = 1.f / cs;
        }
        __syncthreads();

        // updates[s][d] = (sum_n att[s][n] * v[n][d]) * inv_cs[s]
        {
            const int d = t & 63, wq = t >> 6;
            float acc[4] = {0.f, 0.f, 0.f, 0.f};
            for (int n4 = 0; n4 < N_TOK; n4 += 4) {
                float vv[4];
                #pragma unroll
                for (int j = 0; j < 4; ++j) vv[j] = vb[(size_t)(n4 + j) * 64 + d];
                #pragma unroll
                for (int si = 0; si < 4; ++si) {
                    const float4 a4 = *(const float4*)&att[wq * 4 + si][n4];
                    acc[si] += a4.x * vv[0] + a4.y * vv[1] + a4.z * vv[2] + a4.w * vv[3];
                }
            }
            #pragma unroll
            for (int si = 0; si < 4; ++si)
                upd[wq * 4 + si][d] = acc[si] * inv_cs[wq * 4 + si];
        }
        __syncthreads();

        // GRU gates: gi = upd @ W_ih^T + b_ih ; gh = sp @ W_hh^T + b_hh
        {
            const int s = t >> 4, g0 = t & 15;
            float accI[12], accH[12];
            #pragma unroll
            for (int j = 0; j < 12; ++j) { accI[j] = b_ih[g0 + 16 * j]; accH[j] = b_hh[g0 + 16 * j]; }
            for (int dq = 0; dq < 16; ++dq) {
                const float4 u4 = *(const float4*)&upd[s][dq * 4];
                const float4 h4 = *(const float4*)&sp[s][dq * 4];
                #pragma unroll
                for (int j = 0; j < 12; ++j) {
                    const int g = g0 + 16 * j;
                    const float4 wi = *(const float4*)&W_ih[(size_t)g * 64 + dq * 4];
                    const float4 wh = *(const float4*)&W_hh[(size_t)g * 64 + dq * 4];
                    accI[j] += u4.x * wi.x + u4.y * wi.y + u4.z * wi.z + u4.w * wi.w;
                    accH[j] += h4.x * wh.x + h4.y * wh.y + h4.z * wh.z + h4.w * wh.w;
                }
            }
            #pragma unroll
            for (int j = 0; j < 12; ++j) { gi_l[s][g0 + 16 * j] = accI[j]; gh_l[s][g0 + 16 * j] = accH[j]; }
        }
        __syncthreads();

        // combine gates -> new slots (GRU cell)
        {
            const int s = t >> 4, d0 = t & 15;
            #pragma unroll
            for (int m = 0; m < 4; ++m) {
                const int d = d0 + 16 * m;
                const float r  = sigmoid_f(gi_l[s][d] + gh_l[s][d]);
                const float z  = sigmoid_f(gi_l[s][64 + d] + gh_l[s][64 + d]);
                const float nc = tanh_f(gi_l[s][128 + d] + r * gh_l[s][128 + d]);
                slots[s][d] = (1.f - z) * nc + z * sp[s][d];
            }
        }
        __syncthreads();

        // LN(slots) with ln_out -> lnbuf
        {
            const int s = t >> 4, j = t & 15;
            const float4 x = *(const float4*)&slots[s][j * 4];
            float sum = x.x + x.y + x.z + x.w;
            float ssm = x.x * x.x + x.y * x.y + x.z * x.z + x.w * x.w;
            #pragma unroll
            for (int m = 8; m >= 1; m >>= 1) { sum += __shfl_xor(sum, m, 64); ssm += __shfl_xor(ssm, m, 64); }
            const float mean = sum * (1.f / 64);
            const float rstd = rsqrtf(ssm * (1.f / 64) - mean * mean + 1e-5f);
            const int d0 = j * 4;
            lnbuf[s][d0 + 0] = (x.x - mean) * rstd * lnow[d0 + 0] + lnob[d0 + 0];
            lnbuf[s][d0 + 1] = (x.y - mean) * rstd * lnow[d0 + 1] + lnob[d0 + 1];
            lnbuf[s][d0 + 2] = (x.z - mean) * rstd * lnow[d0 + 2] + lnob[d0 + 2];
            lnbuf[s][d0 + 3] = (x.w - mean) * rstd * lnow[d0 + 3] + lnob[d0 + 3];
        }
        __syncthreads();

        // mlp1 = relu(lnbuf @ W1^T + b1)
        {
            const int o = t & 63, wq = t >> 6;
            float acc[4];
            #pragma unroll
            for (int si = 0; si < 4; ++si) acc[si] = b1[o];
            for (int iq = 0; iq < 16; ++iq) {
                const float4 w4 = *(const float4*)&W1[(size_t)o * 64 + iq * 4];
                #pragma unroll
                for (int si = 0; si < 4; ++si) {
                    const float4 l4 = *(const float4*)&lnbuf[wq * 4 + si][iq * 4];
                    acc[si] += l4.x * w4.x + l4.y * w4.y + l4.z * w4.z + l4.w * w4.w;
                }
            }
            #pragma unroll
            for (int si = 0; si < 4; ++si) mlp_l[wq * 4 + si][o] = fmaxf(acc[si], 0.f);
        }
        __syncthreads();

        // slots += mlp_l @ W2^T + b2
        {
            const int o = t & 63, wq = t >> 6;
            float acc[4];
            #pragma unroll
            for (int si = 0; si < 4; ++si) acc[si] = b2[o];
            for (int iq = 0; iq < 16; ++iq) {
                const float4 w4 = *(const float4*)&W2[(size_t)o * 64 + iq * 4];
                #pragma unroll
                for (int si = 0; si < 4; ++si) {
                    const float4 l4 = *(const float4*)&mlp_l[wq * 4 + si][iq * 4];
                    acc[si] += l4.x * w4.x + l4.y * w4.y + l4.z * w4.z + l4.w * w4.w;
                }
            }
            #pragma unroll
            for (int si = 0; si < 4; ++si) slots[wq * 4 + si][o] += acc[si];
        }
        __syncthreads();
    }

    // write slots transposed: slots_T[d][b*16+s]
    {
        const int s = t >> 4, d0 = (t & 15) * 4;
        #pragma unroll
        for (int dd = 0; dd < 4; ++dd)
            slots_T[(size_t)(d0 + dd) * TOT_SLOT_ROWS + b * 16 + s] = slots[s][d0 + dd];
    }
}

// ---------------------------------------------------------------------------
// Kernel C: prompts[row][n] = sum_h slots[row][h] * s2p[h][n]  (f32 out)
// 16 rows x 2048 cols per block; acc[16] stays in VGPRs (no spill).
// colgrp-major block order: consecutive blocks share the same s2p slice (L2).
// ---------------------------------------------------------------------------
__global__ __launch_bounds__(256) void prompt_kernel(
    const float* __restrict__ slots_T, const float* __restrict__ s2p,
    float* __restrict__ out)
{
    const int idx = blockIdx.x;
    const int colgrp = idx >> 7;      // 0..14
    const int rowgrp = idx & 127;     // 0..127
    const int rowbase = rowgrp * 16;
    const int t = threadIdx.x;

    #pragma unroll 1
    for (int j = 0; j < 8; ++j) {
        const int n = colgrp * 2048 + j * 256 + t;
        float acc[16];
        #pragma unroll
        for (int r = 0; r < 16; ++r) acc[r] = 0.f;
        #pragma unroll 2
        for (int h = 0; h < 64; ++h) {
            const float sv = s2p[(size_t)h * PROMPT_N + n];
            const float* sl = slots_T + (size_t)h * TOT_SLOT_ROWS + rowbase; // uniform -> s_load
            #pragma unroll
            for (int r = 0; r < 16; ++r) acc[r] = fmaf(sl[r], sv, acc[r]);
        }
        #pragma unroll
        for (int r = 0; r < 16; ++r)
            out[(size_t)(rowbase + r) * PROMPT_N + n] = acc[r];
    }
}

// ---------------------------------------------------------------------------
extern "C" void kernel_launch(void* const* d_in, const int* in_sizes, int n_in,
                              void* d_out, int out_size, void* d_ws, size_t ws_size,
                              hipStream_t stream)
{
    (void)in_sizes; (void)n_in; (void)out_size; (void)ws_size;
    const float* feat    = (const float*)d_in[0];
    const float* noise   = (const float*)d_in[1];
    const float* ln_in_w = (const float*)d_in[2];
    const float* ln_in_b = (const float*)d_in[3];
    const float* ln_s_w  = (const float*)d_in[4];
    const float* ln_s_b  = (const float*)d_in[5];
    const float* ln_o_w  = (const float*)d_in[6];
    const float* ln_o_b  = (const float*)d_in[7];
    const float* mu      = (const float*)d_in[8];
    const float* sigma   = (const float*)d_in[9];
    const float* Wk      = (const float*)d_in[10];
    const float* Wq      = (const float*)d_in[11];
    const float* Wv      = (const float*)d_in[12];
    const float* W_ih    = (const float*)d_in[13];
    const float* W_hh    = (const float*)d_in[14];
    const float* b_ih    = (const float*)d_in[15];
    const float* b_hh    = (const float*)d_in[16];
    const float* W1      = (const float*)d_in[17];
    const float* b1      = (const float*)d_in[18];
    const float* W2      = (const float*)d_in[19];
    const float* b2      = (const float*)d_in[20];
    const float* s2p     = (const float*)d_in[21];

    float* kbuf    = (float*)d_ws;
    float* vbuf    = kbuf + (size_t)N_ROWS * 64;
    float* slots_T = vbuf + (size_t)N_ROWS * 64;

    hipLaunchKernelGGL(kv_kernel, dim3(N_ROWS / 16), dim3(256), 0, stream,
                       feat, ln_in_w, ln_in_b, Wk, Wv, kbuf, vbuf);
    hipLaunchKernelGGL(iter_kernel, dim3(BS), dim3(256), 0, stream,
                       kbuf, vbuf, noise, mu, sigma, ln_s_w, ln_s_b, ln_o_w, ln_o_b,
                       Wq, W_ih, W_hh, b_ih, b_hh, W1, b1, W2, b2, slots_T);
    hipLaunchKernelGGL(prompt_kernel, dim3(15 * 128), dim3(256), 0, stream,
                       slots_T, s2p, (float*)d_out);
}